// Round 1
// baseline (1622.823 us; speedup 1.0000x reference)
//
#include <hip/hip_runtime.h>

#define S 2048
#define DM 1024
#define NH 16
#define DK 64
#define BATCH 4

typedef float f4 __attribute__((ext_vector_type(4)));
typedef __bf16 bf16x8 __attribute__((ext_vector_type(8)));

#define MFMA(a, b, c) __builtin_amdgcn_mfma_f32_16x16x32_bf16(a, b, c, 0, 0, 0)

__device__ __forceinline__ unsigned short f2bf(float f) {
  union { float f; unsigned int u; } x; x.f = f;
  return (unsigned short)((x.u + 0x7FFFu + ((x.u >> 16) & 1u)) >> 16);
}

__device__ __forceinline__ unsigned int pack2(float a, float b) {
  return (unsigned int)f2bf(a) | ((unsigned int)f2bf(b) << 16);
}

// stage 8 consecutive fp32 -> 8 bf16 (one 16B LDS write)
__device__ __forceinline__ void stage8(const float* __restrict__ src,
                                       unsigned short* dst) {
  float4 a = ((const float4*)src)[0];
  float4 b = ((const float4*)src)[1];
  uint4 p;
  p.x = pack2(a.x, a.y); p.y = pack2(a.z, a.w);
  p.z = pack2(b.x, b.y); p.w = pack2(b.z, b.w);
  *(uint4*)dst = p;
}

// stage 16 consecutive bf16 (two 16B copies)
__device__ __forceinline__ void stage16bf(const unsigned short* __restrict__ src,
                                          unsigned short* dst) {
  uint4 a = ((const uint4*)src)[0];
  uint4 b = ((const uint4*)src)[1];
  ((uint4*)dst)[0] = a;
  ((uint4*)dst)[1] = b;
}

// ---------------------------------------------------------------------------
// Y[M,N] = X[M,K] @ W[N,K]^T (+ res), fp32 inputs, bf16 MFMA, out fp32 or bf16
// 128x128 tile, BK=32, 4 waves in 2x2, each wave 64x64 (4x4 16x16 MFMA tiles)
// ---------------------------------------------------------------------------
template <bool OUT_BF16, bool RES>
__global__ __launch_bounds__(256)
void gemm_xwt(const float* __restrict__ X, const float* __restrict__ W,
              const float* __restrict__ res, void* __restrict__ Yv,
              int M, int N, int K) {
  const int LDA = 40;  // 32 + 8 pad (keeps 16B alignment, breaks pow2 stride)
  __shared__ alignas(16) unsigned short As[128 * LDA];
  __shared__ alignas(16) unsigned short Bs[128 * LDA];

  const int tid = threadIdx.x;
  const int wid = tid >> 6, lane = tid & 63;
  const int g = lane >> 4, c = lane & 15;
  const int m0 = blockIdx.y * 128, n0 = blockIdx.x * 128;
  const int wm = (wid >> 1) * 64, wn = (wid & 1) * 64;

  f4 acc[4][4];
#pragma unroll
  for (int i = 0; i < 4; i++)
#pragma unroll
    for (int j = 0; j < 4; j++) acc[i][j] = (f4){0.f, 0.f, 0.f, 0.f};

  const int srow = tid >> 2;       // 0..63
  const int sk = (tid & 3) * 8;    // 0,8,16,24

  for (int k0 = 0; k0 < K; k0 += 32) {
#pragma unroll
    for (int rr = 0; rr < 128; rr += 64) {
      stage8(X + (size_t)(m0 + srow + rr) * K + k0 + sk,
             &As[(srow + rr) * LDA + sk]);
      stage8(W + (size_t)(n0 + srow + rr) * K + k0 + sk,
             &Bs[(srow + rr) * LDA + sk]);
    }
    __syncthreads();
    bf16x8 av[4], bv[4];
#pragma unroll
    for (int i = 0; i < 4; i++)
      av[i] = *(const bf16x8*)&As[(wm + i * 16 + c) * LDA + g * 8];
#pragma unroll
    for (int j = 0; j < 4; j++)
      bv[j] = *(const bf16x8*)&Bs[(wn + j * 16 + c) * LDA + g * 8];
#pragma unroll
    for (int i = 0; i < 4; i++)
#pragma unroll
      for (int j = 0; j < 4; j++)
        acc[i][j] = MFMA(av[i], bv[j], acc[i][j]);
    __syncthreads();
  }

#pragma unroll
  for (int i = 0; i < 4; i++) {
#pragma unroll
    for (int j = 0; j < 4; j++) {
      const int row = m0 + wm + i * 16 + g * 4;
      const int col = n0 + wn + j * 16 + c;
#pragma unroll
      for (int r = 0; r < 4; r++) {
        size_t off = (size_t)(row + r) * N + col;
        float vv = acc[i][j][r];
        if constexpr (RES) vv += res[off];
        if constexpr (OUT_BF16)
          ((unsigned short*)Yv)[off] = f2bf(vv);
        else
          ((float*)Yv)[off] = vv;
      }
    }
  }
}

// ---------------------------------------------------------------------------
// Fused attention: per workgroup = one (b, h, 64 q rows).
// Pass 1: stream 32 K-tiles, online row max/sumexp.  Pass 2: recompute scores,
// write normalized attn to d_out, P->LDS->A-frags, ctx += P @ V.
// Qp/Kp/Vp are bf16 [B][H][S][64] (contiguous per head via the view quirk).
// ---------------------------------------------------------------------------
__global__ __launch_bounds__(256)
void attn_kernel(const unsigned short* __restrict__ Qp,
                 const unsigned short* __restrict__ Kp,
                 const unsigned short* __restrict__ Vp,
                 float* __restrict__ attnOut, float* __restrict__ ctxOut) {
  const int LDA = 72;  // 64 + 8 pad
  __shared__ alignas(16) unsigned short Qs[64 * LDA];
  __shared__ alignas(16) unsigned short Ks[64 * LDA];
  __shared__ alignas(16) unsigned short Vt[64 * LDA];
  __shared__ alignas(16) unsigned short Ps[4][16 * LDA];

  const int tid = threadIdx.x;
  const int wid = tid >> 6, lane = tid & 63;
  const int g = lane >> 4, c = lane & 15;

  const int bid = blockIdx.x;
  const int qb = bid & 31;          // S/64 = 32 q-blocks
  const int h = (bid >> 5) & 15;
  const int b = bid >> 9;

  const size_t headOff = ((size_t)b * NH + h) * S * DK;
  const unsigned short* Qh = Qp + headOff;
  const unsigned short* Kh = Kp + headOff;
  const unsigned short* Vh = Vp + headOff;
  float* attnB = attnOut + (((size_t)b * NH + h) * S + (size_t)qb * 64) * S;

  const int srow = tid >> 2;        // 0..63
  const int sd = (tid & 3) * 16;    // 0,16,32,48

  stage16bf(Qh + (size_t)(qb * 64 + srow) * DK + sd, &Qs[srow * LDA + sd]);
  __syncthreads();

  const bf16x8 qa0 = *(const bf16x8*)&Qs[(wid * 16 + c) * LDA + g * 8];
  const bf16x8 qa1 = *(const bf16x8*)&Qs[(wid * 16 + c) * LDA + 32 + g * 8];

  float mrow[4], lrow[4];
#pragma unroll
  for (int r = 0; r < 4; r++) { mrow[r] = -1e30f; lrow[r] = 0.f; }

  const float scale = 0.125f;  // 1/sqrt(64)

  // ---- pass 1: row max + sumexp ----
  for (int kt = 0; kt < 32; kt++) {
    __syncthreads();
    stage16bf(Kh + (size_t)(kt * 64 + srow) * DK + sd, &Ks[srow * LDA + sd]);
    __syncthreads();

    f4 sf[4];
#pragma unroll
    for (int f = 0; f < 4; f++) {
      bf16x8 b0 = *(const bf16x8*)&Ks[(f * 16 + c) * LDA + g * 8];
      bf16x8 b1 = *(const bf16x8*)&Ks[(f * 16 + c) * LDA + 32 + g * 8];
      f4 s = (f4){0.f, 0.f, 0.f, 0.f};
      s = MFMA(qa0, b0, s);
      s = MFMA(qa1, b1, s);
      sf[f] = s * scale;
    }
    float tm[4], ps[4];
#pragma unroll
    for (int r = 0; r < 4; r++)
      tm[r] = fmaxf(fmaxf(sf[0][r], sf[1][r]), fmaxf(sf[2][r], sf[3][r]));
#pragma unroll
    for (int mask = 1; mask < 16; mask <<= 1)
#pragma unroll
      for (int r = 0; r < 4; r++)
        tm[r] = fmaxf(tm[r], __shfl_xor(tm[r], mask));
#pragma unroll
    for (int r = 0; r < 4; r++) {
      float nm = fmaxf(mrow[r], tm[r]);
      ps[r] = __expf(sf[0][r] - nm) + __expf(sf[1][r] - nm) +
              __expf(sf[2][r] - nm) + __expf(sf[3][r] - nm);
      lrow[r] = lrow[r] * __expf(mrow[r] - nm);
      mrow[r] = nm;
    }
#pragma unroll
    for (int mask = 1; mask < 16; mask <<= 1)
#pragma unroll
      for (int r = 0; r < 4; r++) ps[r] += __shfl_xor(ps[r], mask);
#pragma unroll
    for (int r = 0; r < 4; r++) lrow[r] += ps[r];
  }

  float rl[4];
#pragma unroll
  for (int r = 0; r < 4; r++) rl[r] = 1.f / lrow[r];

  f4 ctxv[4];
#pragma unroll
  for (int f = 0; f < 4; f++) ctxv[f] = (f4){0.f, 0.f, 0.f, 0.f};

  const int vk = tid & 63;           // k_local for V staging
  const int vd = (tid >> 6) * 16;    // d0 for V staging

  // ---- pass 2: attn out + ctx accumulate ----
  for (int kt = 0; kt < 32; kt++) {
    __syncthreads();
    stage16bf(Kh + (size_t)(kt * 64 + srow) * DK + sd, &Ks[srow * LDA + sd]);
    {
      const unsigned short* vp = Vh + (size_t)(kt * 64 + vk) * DK + vd;
      uint4 a = ((const uint4*)vp)[0];
      uint4 bq = ((const uint4*)vp)[1];
      unsigned short vals[16];
      vals[0] = a.x & 0xFFFF;  vals[1] = a.x >> 16;
      vals[2] = a.y & 0xFFFF;  vals[3] = a.y >> 16;
      vals[4] = a.z & 0xFFFF;  vals[5] = a.z >> 16;
      vals[6] = a.w & 0xFFFF;  vals[7] = a.w >> 16;
      vals[8] = bq.x & 0xFFFF; vals[9] = bq.x >> 16;
      vals[10] = bq.y & 0xFFFF; vals[11] = bq.y >> 16;
      vals[12] = bq.z & 0xFFFF; vals[13] = bq.z >> 16;
      vals[14] = bq.w & 0xFFFF; vals[15] = bq.w >> 16;
#pragma unroll
      for (int i = 0; i < 16; i++) Vt[(vd + i) * LDA + vk] = vals[i];
    }
    __syncthreads();

    f4 pf[4];
#pragma unroll
    for (int f = 0; f < 4; f++) {
      bf16x8 b0 = *(const bf16x8*)&Ks[(f * 16 + c) * LDA + g * 8];
      bf16x8 b1 = *(const bf16x8*)&Ks[(f * 16 + c) * LDA + 32 + g * 8];
      f4 s = (f4){0.f, 0.f, 0.f, 0.f};
      s = MFMA(qa0, b0, s);
      s = MFMA(qa1, b1, s);
#pragma unroll
      for (int r = 0; r < 4; r++)
        pf[f][r] = __expf(s[r] * scale - mrow[r]) * rl[r];
    }
    // write normalized attn (fp32) to d_out
    float* ap = attnB + (size_t)(wid * 16 + g * 4) * S + kt * 64;
#pragma unroll
    for (int f = 0; f < 4; f++)
#pragma unroll
      for (int r = 0; r < 4; r++)
        ap[(size_t)r * S + f * 16 + c] = pf[f][r];
    // P -> LDS (C-layout scatter), then re-read in A-layout
#pragma unroll
    for (int f = 0; f < 4; f++)
#pragma unroll
      for (int r = 0; r < 4; r++)
        Ps[wid][(g * 4 + r) * LDA + f * 16 + c] = f2bf(pf[f][r]);
    __syncthreads();

    bf16x8 pa0 = *(const bf16x8*)&Ps[wid][c * LDA + g * 8];
    bf16x8 pa1 = *(const bf16x8*)&Ps[wid][c * LDA + 32 + g * 8];
#pragma unroll
    for (int f = 0; f < 4; f++) {
      bf16x8 v0 = *(const bf16x8*)&Vt[(f * 16 + c) * LDA + g * 8];
      bf16x8 v1 = *(const bf16x8*)&Vt[(f * 16 + c) * LDA + 32 + g * 8];
      ctxv[f] = MFMA(pa0, v0, ctxv[f]);
      ctxv[f] = MFMA(pa1, v1, ctxv[f]);
    }
  }

  // ctx -> [B][S][H*64] fp32 for the fc GEMM
  float* cp = ctxOut +
              ((size_t)b * S + (size_t)qb * 64 + wid * 16 + g * 4) * DM + h * 64;
#pragma unroll
  for (int f = 0; f < 4; f++)
#pragma unroll
    for (int r = 0; r < 4; r++)
      cp[(size_t)r * DM + f * 16 + c] = ctxv[f][r];
}

// ---------------------------------------------------------------------------
// In-place LayerNorm over rows of 1024.
// ---------------------------------------------------------------------------
__global__ __launch_bounds__(256)
void ln_kernel(float* __restrict__ X, const float* __restrict__ gamma,
               const float* __restrict__ beta) {
  __shared__ float ws[4], ws2[4];
  const int row = blockIdx.x;
  const int tid = threadIdx.x;
  const int wid = tid >> 6, lane = tid & 63;
  float* xp = X + (size_t)row * DM + tid * 4;
  float4 v = *(const float4*)xp;
  float s = v.x + v.y + v.z + v.w;
  float s2 = v.x * v.x + v.y * v.y + v.z * v.z + v.w * v.w;
#pragma unroll
  for (int m = 1; m < 64; m <<= 1) {
    s += __shfl_xor(s, m);
    s2 += __shfl_xor(s2, m);
  }
  if (lane == 0) { ws[wid] = s; ws2[wid] = s2; }
  __syncthreads();
  s = ws[0] + ws[1] + ws[2] + ws[3];
  s2 = ws2[0] + ws2[1] + ws2[2] + ws2[3];
  const float mean = s * (1.f / 1024.f);
  const float var = s2 * (1.f / 1024.f) - mean * mean;
  const float rstd = rsqrtf(var + 1e-6f);
  float4 gg = *(const float4*)(gamma + tid * 4);
  float4 bb = *(const float4*)(beta + tid * 4);
  float4 o;
  o.x = (v.x - mean) * rstd * gg.x + bb.x;
  o.y = (v.y - mean) * rstd * gg.y + bb.y;
  o.z = (v.z - mean) * rstd * gg.z + bb.z;
  o.w = (v.w - mean) * rstd * gg.w + bb.w;
  *(float4*)xp = o;
}

extern "C" void kernel_launch(void* const* d_in, const int* in_sizes, int n_in,
                              void* d_out, int out_size, void* d_ws,
                              size_t ws_size, hipStream_t stream) {
  const float* q = (const float*)d_in[0];
  const float* k = (const float*)d_in[1];
  const float* v = (const float*)d_in[2];
  const float* w_qs = (const float*)d_in[3];
  const float* w_ks = (const float*)d_in[4];
  const float* w_vs = (const float*)d_in[5];
  const float* w_fc = (const float*)d_in[6];
  const float* gamma = (const float*)d_in[7];
  const float* beta = (const float*)d_in[8];

  const size_t projN = (size_t)BATCH * S * DM;  // 8388608
  float* out = (float*)d_out;                   // x / LN region [B,S,1024]
  float* attnO = out + projN;                   // attn region [B,H,S,S]

  // workspace: Qp/Kp/Vp bf16 (16 MB each), ctx fp32 (32 MB) = 80 MB total
  unsigned short* Qp = (unsigned short*)d_ws;
  unsigned short* Kp = Qp + projN;
  unsigned short* Vp = Kp + projN;
  float* Ctx = (float*)(Vp + projN);

  const int M = BATCH * S;  // 8192
  dim3 gg(DM / 128, M / 128);  // (8, 64)

  gemm_xwt<true, false><<<gg, 256, 0, stream>>>(q, w_qs, nullptr, Qp, M, DM, DM);
  gemm_xwt<true, false><<<gg, 256, 0, stream>>>(k, w_ks, nullptr, Kp, M, DM, DM);
  gemm_xwt<true, false><<<gg, 256, 0, stream>>>(v, w_vs, nullptr, Vp, M, DM, DM);

  attn_kernel<<<BATCH * NH * (S / 64), 256, 0, stream>>>(Qp, Kp, Vp, attnO, Ctx);

  gemm_xwt<false, true><<<gg, 256, 0, stream>>>(Ctx, w_fc, q, out, M, DM, DM);

  ln_kernel<<<M, 256, 0, stream>>>(out, gamma, beta);
}